// Round 13
// baseline (1110.876 us; speedup 1.0000x reference)
//
#include <hip/hip_runtime.h>

typedef __attribute__((ext_vector_type(8))) short short8;   // 8 x bf16
typedef __attribute__((ext_vector_type(4))) short short4v;  // 4 x bf16
typedef __attribute__((ext_vector_type(4))) float f32x4;

__device__ __forceinline__ float lrelu_f(float v) { return v > 0.f ? v : 0.01f * v; }
__device__ __forceinline__ short f2bf(float f) {
    unsigned u = __float_as_uint(f);
    return (short)((u + 0x7FFFu + ((u >> 16) & 1u)) >> 16);    // RNE
}
__device__ __forceinline__ float bf2f(unsigned short h) {
    return __uint_as_float(((unsigned)h) << 16);
}
// perm pos p = (c&15)*4 + (c>>4); p2t = inverse, t2p = forward
__device__ __forceinline__ int p2t(int p) { return ((p & 3) << 4) | (p >> 2); }
__device__ __forceinline__ int t2p(int c) { return ((c & 15) << 2) | (c >> 4); }

// weight fragment emit: dst layout ((k*4+ct)*KS+kk)*512 + lane*8 + r
__device__ __forceinline__ void emit_frag(const float* __restrict__ src, short* __restrict__ dst,
                                          int j, int KS, int permIn)
{
    int r = j & 7, lane = (j >> 3) & 63, rem = j >> 9;
    int kk = (KS == 2) ? (rem & 1) : 0;
    rem = (KS == 2) ? (rem >> 1) : rem;
    int ct = rem & 3, k = rem >> 2;
    int cinf = kk * 32 + ((lane >> 4) << 3) + r;
    int cin = permIn ? p2t(cinf) : cinf;
    int cout = ct * 16 + (lane & 15);
    int CIN = KS * 32;
    dst[j] = f2bf(src[(size_t)k * CIN * 64 + (size_t)cin * 64 + cout]);
}

// slot reservation worker (blocks of 2048 entries in [eLo,eHi))
__device__ __forceinline__ void do_reserve(
    const int* __restrict__ io, int eLo, int eHi,
    int* __restrict__ C, int* __restrict__ pos, int lb,
    int mode, int P, int M, int k1, int k2, int k3)
{
    const int e0 = eLo + lb * 2048 + (int)threadIdx.x * 8;
    if (e0 >= eHi) return;
    if (mode == 1 && e0 + 8 <= eHi) {
        int4 v0 = *(const int4*)(io + e0);
        int4 v1 = *(const int4*)(io + e0 + 4);
        int o[8] = {v0.x, v0.y, v0.z, v0.w, v1.x, v1.y, v1.z, v1.w};
        int p[8];
        #pragma unroll
        for (int j = 0; j < 8; ++j) p[j] = atomicAdd(&C[o[j]], 1);
        int4 r0 = {p[0], p[1], p[2], p[3]}, r1 = {p[4], p[5], p[6], p[7]};
        *(int4*)(pos + e0) = r0;
        *(int4*)(pos + e0 + 4) = r1;
    } else {
        for (int e = e0; e < eHi && e < e0 + 8; ++e) {
            int o = io[e];
            int* cp;
            if (mode == 2) {
                int k = e / P;
                int c = (k >= k3) ? 3 : (k >= k2) ? 2 : (k >= k1) ? 1 : 0;
                cp = &C[c * M + o];
            } else cp = &C[o];
            pos[e] = atomicAdd(cp, 1);
        }
    }
}

// converts (blocks < CB) + rb_a reservation (blocks >= CB)
__global__ __launch_bounds__(256) void prep(
    const float* __restrict__ x,  short* __restrict__ xb,  int nx,
    const float* __restrict__ W1, short* __restrict__ W1b,  short* __restrict__ W1f,  int n1,  int f1,
    const float* __restrict__ W12,short* __restrict__ W12b, short* __restrict__ W12f, int n12, int f12,
    const float* __restrict__ W2, short* __restrict__ W2b,  short* __restrict__ W2f,  int n2,  int f2,
    const float* __restrict__ W3, short* __restrict__ W3b,  short* __restrict__ W3f,  int n3,  int f3,
    const float* __restrict__ Wp, short* __restrict__ Wpb,  short* __restrict__ Wpf,  int np,  int fp,
    int CB,
    const int* __restrict__ ria, int rEa, int* __restrict__ rCa, int* __restrict__ rposA)
{
    if ((int)blockIdx.x >= CB) {
        if (ria) do_reserve(ria, 0, rEa, rCa, rposA, blockIdx.x - CB, 1, 0, 0, 0, 0, 0);
        return;
    }
    const int total = nx + n1 + n12 + n2 + n3 + np + f1 + f12 + f2 + f3 + fp;
    for (int i = blockIdx.x * 256 + threadIdx.x; i < total; i += CB * 256) {
        int j = i;
        if (j < nx)  { xb[j]   = f2bf(x[j]);   continue; } j -= nx;
        if (j < n1)  { W1b[j]  = f2bf(W1[j]);  continue; } j -= n1;
        if (j < n12) { W12b[j] = f2bf(W12[j]); continue; } j -= n12;
        if (j < n2)  { W2b[j]  = f2bf(W2[j]);  continue; } j -= n2;
        if (j < n3)  { W3b[j]  = f2bf(W3[j]);  continue; } j -= n3;
        if (j < np)  { Wpb[j]  = f2bf(Wp[j]);  continue; } j -= np;
        if (j < f1)  { emit_frag(W1,  W1f,  j, 1, 0); continue; } j -= f1;
        if (j < f12) { emit_frag(W12, W12f, j, 2, 1); continue; } j -= f12;
        if (j < f2)  { emit_frag(W2,  W2f,  j, 1, 0); continue; } j -= f2;
        if (j < f3)  { emit_frag(W3,  W3f,  j, 2, 1); continue; } j -= f3;
        emit_frag(Wp, Wpf, j, 2, 1);
    }
}

// slot-direct conv (lean, no BN); piggybacked reservation on tail blocks.
template<int CIN, bool OVF_TRUE>
__global__ __launch_bounds__(256) void spconv_slot(
    const short* __restrict__ feats,
    const short* __restrict__ Wf,
    const int*   __restrict__ iin,
    const int*   __restrict__ iout,
    const int*   __restrict__ pos,
    int P, int kLo, int kHi, int tilesPerK, int wavesPerK, int TPW,
    int cap, short* __restrict__ yslot, float* __restrict__ outAcc,
    int convBlocks,
    const int* __restrict__ rio, int rLo, int rHi,
    int* __restrict__ rC, int* __restrict__ rpos,
    int rmode, int rM, int rk1, int rk2, int rk3)
{
    if ((int)blockIdx.x >= convBlocks) {
        if (rmode) do_reserve(rio, rLo, rHi, rC, rpos, blockIdx.x - convBlocks,
                              rmode, P, rM, rk1, rk2, rk3);
        return;
    }
    constexpr int KS = CIN / 32;
    const int lane = threadIdx.x & 63;
    int wid = blockIdx.x * 4 + (threadIdx.x >> 6);
    wid = __builtin_amdgcn_readfirstlane(wid);
    const int k = kLo + wid / wavesPerK;
    if (k >= kHi) return;
    const int wslot = wid % wavesPerK;
    int t0 = wslot * TPW;
    if (t0 >= tilesPerK) return;
    const int t1 = (t0 + TPW < tilesPerK) ? t0 + TPW : tilesPerK;
    const int kBase = k * P, kEnd = kBase + P;
    const int col = lane & 15, g = lane >> 4;

    short8 bf[KS][4];
    const short* wkf = Wf + (size_t)k * 4 * KS * 512;
    #pragma unroll
    for (int ct = 0; ct < 4; ++ct)
        #pragma unroll
        for (int kk = 0; kk < KS; ++kk)
            bf[kk][ct] = *(const short8*)(wkf + ((size_t)(ct * KS + kk) << 9) + lane * 8);

    for (int t = t0; t < t1; ++t) {
        const int base = kBase + t * 16;
        int rr = -1, pp = 0;
        if (lane < 16) {
            int ee = base + lane;
            if (ee < kEnd) { rr = iout[ee]; pp = pos[ee]; }
        }
        int ein = base + col;
        if (ein >= kEnd) ein = kEnd - 1;
        const int rin = iin[ein];
        short8 af[KS];
        const short* fr = feats + (size_t)rin * CIN + g * 8;
        #pragma unroll
        for (int kk = 0; kk < KS; ++kk)
            af[kk] = *(const short8*)(fr + kk * 32);

        f32x4 acc[4] = {f32x4{0,0,0,0}, f32x4{0,0,0,0}, f32x4{0,0,0,0}, f32x4{0,0,0,0}};
        #pragma unroll
        for (int kk = 0; kk < KS; ++kk)
            #pragma unroll
            for (int ct = 0; ct < 4; ++ct)
                acc[ct] = __builtin_amdgcn_mfma_f32_16x16x32_bf16(af[kk], bf[kk][ct], acc[ct], 0, 0, 0);

        #pragma unroll
        for (int j = 0; j < 4; ++j) {
            const int er = base + g * 4 + j;
            const int r2 = __shfl(rr, g * 4 + j);
            const int p2 = __shfl(pp, g * 4 + j);
            if (er < kEnd && r2 >= 0) {
                if (p2 < cap) {
                    short4v v = { f2bf(acc[0][j]), f2bf(acc[1][j]), f2bf(acc[2][j]), f2bf(acc[3][j]) };
                    *(short4v*)(yslot + ((size_t)r2 * cap + p2) * 64 + col * 4) = v;
                } else {
                    float* op = outAcc + (size_t)r2 * 64;
                    #pragma unroll
                    for (int ct = 0; ct < 4; ++ct)
                        atomicAdd(op + (OVF_TRUE ? ct * 16 + col : col * 4 + ct), acc[ct][j]);
                }
            }
        }
    }
}

// slot-window reduce, R rows/wave; accumulates into out; optional fused
// BN-stats (sum/sumsq of lrelu(final), perm-indexed).
template<bool UNPERM>
__global__ __launch_bounds__(256) void reduce_slot(
    const short* __restrict__ yslot, const int* __restrict__ C, int cap,
    float* __restrict__ out, int nRows, int R, float* __restrict__ stats)
{
    __shared__ float sred[2][4][64];
    const int lane = threadIdx.x & 63;
    const int wib  = threadIdx.x >> 6;
    const int r0 = (blockIdx.x * 4 + wib) * R;
    float st_s = 0.f, st_q = 0.f;
    for (int r = r0; r < r0 + R && r < nRows; ++r) {
        int cnt = C[r]; if (cnt > cap) cnt = cap;
        const unsigned short* basep = (const unsigned short*)yslot + (size_t)r * cap * 64 + lane;
        float a0 = 0.f, a1 = 0.f, a2 = 0.f, a3 = 0.f;
        int s = 0;
        for (; s + 4 <= cnt; s += 4) {
            a0 += bf2f(basep[(s + 0) * 64]);
            a1 += bf2f(basep[(s + 1) * 64]);
            a2 += bf2f(basep[(s + 2) * 64]);
            a3 += bf2f(basep[(s + 3) * 64]);
        }
        for (; s < cnt; ++s) a0 += bf2f(basep[s * 64]);
        const int op_c = UNPERM ? p2t(lane) : lane;
        float* op = out + (size_t)r * 64 + op_c;
        float fin = *op + ((a0 + a1) + (a2 + a3));
        *op = fin;
        if (stats) { float v = lrelu_f(fin); st_s += v; st_q += v * v; }
    }
    if (stats) {
        sred[0][wib][lane] = st_s; sred[1][wib][lane] = st_q;
        __syncthreads();
        if (wib == 0) {
            float ss = sred[0][0][lane] + sred[0][1][lane] + sred[0][2][lane] + sred[0][3][lane];
            float qq = sred[1][0][lane] + sred[1][1][lane] + sred[1][2][lane] + sred[1][3][lane];
            atomicAdd(&stats[lane], ss);
            atomicAdd(&stats[64 + lane], qq);
        }
    }
}

// t_bf = bf16(bn(lrelu(A))) in perm space; optionally zeroes A after read.
__global__ __launch_bounds__(256) void bn_apply(
    float* __restrict__ A, const float* __restrict__ stats,
    const float* __restrict__ gamma, const float* __restrict__ beta,
    short* __restrict__ out_bf, int n, int zeroA)
{
    const int c = threadIdx.x & 63;           // perm pos
    const float inv_n = 1.0f / (float)n;
    const float m   = stats[c] * inv_n;
    const float var = stats[64 + c] * inv_n - m * m;
    const float sc  = rsqrtf(var + 1e-5f) * gamma[p2t(c)];
    const float bb  = beta[p2t(c)] - m * sc;
    const long total = (long)n * 64;
    const long stride = (long)gridDim.x * blockDim.x;
    for (long i = (long)blockIdx.x * blockDim.x + threadIdx.x; i < total; i += stride) {
        float r = lrelu_f(A[i]) * sc + bb;
        out_bf[i] = f2bf(r);
        if (zeroA) A[i] = 0.f;
    }
}

// final: resA = bn3(lrelu(resA_raw)) + bn1(lrelu(A1)); also bf16 perm copy
__global__ __launch_bounds__(256) void apply4(
    float* __restrict__ resA, const float* __restrict__ st3,
    const float* __restrict__ g2, const float* __restrict__ b2,
    const float* __restrict__ A1, const float* __restrict__ st1,
    const float* __restrict__ g02, const float* __restrict__ b02,
    short* __restrict__ rA_bf, int n)
{
    const int tc = threadIdx.x & 63;
    const int p  = t2p(tc);
    const float inv_n = 1.0f / (float)n;
    float m3 = st3[p] * inv_n, v3 = st3[64 + p] * inv_n - m3 * m3;
    float sc3 = rsqrtf(v3 + 1e-5f) * g2[tc], bb3 = b2[tc] - m3 * sc3;
    float m1 = st1[p] * inv_n, v1 = st1[64 + p] * inv_n - m1 * m1;
    float sc1 = rsqrtf(v1 + 1e-5f) * g02[tc], bb1 = b02[tc] - m1 * sc1;
    const long total = (long)n * 64;
    const long stride = (long)gridDim.x * blockDim.x;
    for (long i = (long)blockIdx.x * blockDim.x + threadIdx.x; i < total; i += stride) {
        long row = i >> 6;
        float r3 = lrelu_f(resA[i]) * sc3 + bb3;
        float r1 = lrelu_f(A1[(row << 6) + p]) * sc1 + bb1;
        float out = r3 + r1;
        resA[i] = out;
        rA_bf[(row << 6) + p] = f2bf(out);
    }
}

// ---------------- fallback kernels (plain layouts) ----------------
template<int CIN>
__global__ __launch_bounds__(256) void spconv_mfma(
    const short* __restrict__ feats, const short* __restrict__ W,
    const int* __restrict__ iin, const int* __restrict__ iout,
    int P, int tilesPerK, int wavesPerK, int K, int TPW,
    float* __restrict__ out)
{
    constexpr int KS = CIN / 32;
    const int lane = threadIdx.x & 63;
    int wid = blockIdx.x * 4 + (threadIdx.x >> 6);
    wid = __builtin_amdgcn_readfirstlane(wid);
    const int k = wid / wavesPerK;
    if (k >= K) return;
    const int wslot = wid % wavesPerK;
    int t0 = wslot * TPW;
    if (t0 >= tilesPerK) return;
    const int t1 = (t0 + TPW < tilesPerK) ? t0 + TPW : tilesPerK;
    const int kBase = k * P, kEnd = kBase + P;
    const int col = lane & 15, g = lane >> 4;
    short8 bf[KS][4];
    const short* wk = W + (size_t)k * CIN * 64;
    #pragma unroll
    for (int kk = 0; kk < KS; ++kk)
        #pragma unroll
        for (int ct = 0; ct < 4; ++ct)
            #pragma unroll
            for (int r = 0; r < 8; ++r)
                bf[kk][ct][r] = wk[(size_t)(kk * 32 + g * 8 + r) * 64 + ct * 16 + col];
    for (int t = t0; t < t1; ++t) {
        const int base = kBase + t * 16;
        int ein = base + col;
        if (ein >= kEnd) ein = kEnd - 1;
        const int rin = iin[ein];
        short8 af[KS];
        const short* fr = feats + (size_t)rin * CIN + g * 8;
        #pragma unroll
        for (int kk = 0; kk < KS; ++kk)
            af[kk] = *(const short8*)(fr + kk * 32);
        f32x4 acc[4] = {f32x4{0,0,0,0}, f32x4{0,0,0,0}, f32x4{0,0,0,0}, f32x4{0,0,0,0}};
        #pragma unroll
        for (int kk = 0; kk < KS; ++kk)
            #pragma unroll
            for (int ct = 0; ct < 4; ++ct)
                acc[ct] = __builtin_amdgcn_mfma_f32_16x16x32_bf16(af[kk], bf[kk][ct], acc[ct], 0, 0, 0);
        const int rbase = base + g * 4;
        #pragma unroll
        for (int j = 0; j < 4; ++j) {
            const int er = rbase + j;
            if (er < kEnd) {
                const int rout = iout[er];
                float* op = out + (size_t)rout * 64 + col;
                #pragma unroll
                for (int ct = 0; ct < 4; ++ct)
                    atomicAdd(op + ct * 16, acc[ct][j]);
            }
        }
    }
}

__global__ __launch_bounds__(256) void bn_stats(
    const float* __restrict__ A, int n, float* __restrict__ stats)
{
    __shared__ float ls[256], lq[256];
    float s = 0.f, q = 0.f;
    const long total = (long)n * 64;
    const long stride = (long)gridDim.x * 256;
    for (long i = (long)blockIdx.x * 256 + threadIdx.x; i < total; i += stride) {
        float v = lrelu_f(A[i]);
        s += v; q += v * v;
    }
    ls[threadIdx.x] = s; lq[threadIdx.x] = q;
    __syncthreads();
    if (threadIdx.x < 64) {
        atomicAdd(&stats[threadIdx.x],
                  ls[threadIdx.x] + ls[threadIdx.x + 64] + ls[threadIdx.x + 128] + ls[threadIdx.x + 192]);
        atomicAdd(&stats[64 + threadIdx.x],
                  lq[threadIdx.x] + lq[threadIdx.x + 64] + lq[threadIdx.x + 128] + lq[threadIdx.x + 192]);
    }
}

__global__ __launch_bounds__(256) void bn_apply_fb(
    const float* __restrict__ A, const float* __restrict__ stats,
    const float* __restrict__ gamma, const float* __restrict__ beta,
    float* __restrict__ out_f32, short* __restrict__ out_bf, int n)
{
    const int c = threadIdx.x & 63;
    const float inv_n = 1.0f / (float)n;
    const float m   = stats[c] * inv_n;
    const float var = stats[64 + c] * inv_n - m * m;
    const float sc  = rsqrtf(var + 1e-5f) * gamma[c];
    const float bb  = beta[c] - m * sc;
    const long total = (long)n * 64;
    const long stride = (long)gridDim.x * blockDim.x;
    for (long i = (long)blockIdx.x * blockDim.x + threadIdx.x; i < total; i += stride) {
        float r = lrelu_f(A[i]) * sc + bb;
        if (out_f32) out_f32[i] = r;
        if (out_bf)  out_bf[i] = f2bf(r);
    }
}

// fallback helper: resA += A1 ; t_bf = bf16(resA)
__global__ __launch_bounds__(256) void add_copy(
    float* __restrict__ resA, const float* __restrict__ A1,
    short* __restrict__ t_bf, int n)
{
    const long total = (long)n * 64;
    const long stride = (long)gridDim.x * blockDim.x;
    for (long i = (long)blockIdx.x * blockDim.x + threadIdx.x; i < total; i += stride) {
        float v = resA[i] + A1[i];
        resA[i] = v;
        t_bf[i] = f2bf(v);
    }
}

extern "C" void kernel_launch(void* const* d_in, const int* in_sizes, int n_in,
                              void* d_out, int out_size, void* d_ws, size_t ws_size,
                              hipStream_t stream)
{
    const float* x   = (const float*)d_in[0];
    const float* W1  = (const float*)d_in[1];
    const float* W12 = (const float*)d_in[2];
    const float* W2  = (const float*)d_in[3];
    const float* W3  = (const float*)d_in[4];
    const float* Wp  = (const float*)d_in[5];
    const float* g0  = (const float*)d_in[6];
    const float* b0  = (const float*)d_in[7];
    const float* g02 = (const float*)d_in[8];
    const float* b02 = (const float*)d_in[9];
    const float* g1  = (const float*)d_in[10];
    const float* b1  = (const float*)d_in[11];
    const float* g2  = (const float*)d_in[12];
    const float* b2  = (const float*)d_in[13];
    const int* rb_a_in  = (const int*)d_in[14];
    const int* rb_a_out = (const int*)d_in[15];
    const int* rb_b_in  = (const int*)d_in[16];
    const int* rb_b_out = (const int*)d_in[17];
    const int* rb_p_in  = (const int*)d_in[18];
    const int* rb_p_out = (const int*)d_in[19];

    const int N  = in_sizes[0] / 32;
    const int M  = out_size / 64 - N;
    const int Ea = in_sizes[14];
    const int Eb = in_sizes[16];
    const int Ep = in_sizes[18];
    const int Ka = Ea / N, Kp = Ep / N;
    const int P  = N;

    float* resB = (float*)d_out;
    float* resA = resB + (size_t)M * 64;

    const int f1  = 9 * 4 * 1 * 512, f12 = 9 * 4 * 2 * 512;
    const int f2s = 9 * 4 * 1 * 512, f3  = 9 * 4 * 2 * 512, fp = 27 * 4 * 2 * 512;

    size_t off = 0;
    auto take = [&](size_t bytes) { size_t o = off; off += (bytes + 255) & ~(size_t)255; return o; };
    char* base = (char*)d_ws;
    size_t oA0   = take((size_t)N * 64 * 4);      // stage1/3 f32 accum
    size_t oA1   = take((size_t)N * 64 * 4);      // stage2 f32 accum (shortcut, raw)
    size_t oSh   = take((size_t)N * 64 * 2);      // t_bf (perm bf16 stage input / pool input)
    size_t oxb   = take((size_t)N * 32 * 2);
    size_t oW1   = take((size_t)9 * 32 * 64 * 2);
    size_t oW12  = take((size_t)9 * 64 * 64 * 2);
    size_t oW2   = take((size_t)9 * 32 * 64 * 2);
    size_t oW3   = take((size_t)9 * 64 * 64 * 2);
    size_t oWp   = take((size_t)27 * 64 * 64 * 2);
    size_t oW1f  = take((size_t)f1 * 2);
    size_t oW12f = take((size_t)f12 * 2);
    size_t oW2f  = take((size_t)f2s * 2);
    size_t oW3f  = take((size_t)f3 * 2);
    size_t oWpf  = take((size_t)fp * 2);
    size_t oPa   = take((size_t)Ea * 4);
    size_t oPb   = take((size_t)Eb * 4);
    size_t oPp   = take((size_t)Ep * 4);
    size_t oCNT  = take(((size_t)2 * N + 4 * M + 512) * 4);
    const size_t oDyn = off;

    float* A0    = (float*)(base + oA0);
    float* A1    = (float*)(base + oA1);
    short* t_bf  = (short*)(base + oSh);
    short* x_bf  = (short*)(base + oxb);
    short* W1b   = (short*)(base + oW1);
    short* W12b  = (short*)(base + oW12);
    short* W2b   = (short*)(base + oW2);
    short* W3b   = (short*)(base + oW3);
    short* Wpb   = (short*)(base + oWp);
    short* W1f   = (short*)(base + oW1f);
    short* W12f  = (short*)(base + oW12f);
    short* W2f   = (short*)(base + oW2f);
    short* W3f   = (short*)(base + oW3f);
    short* Wpf   = (short*)(base + oWpf);
    int*   pos_a = (int*)(base + oPa);
    int*   pos_b = (int*)(base + oPb);
    int*   pos_p = (int*)(base + oPp);
    int*   Cbase = (int*)(base + oCNT);
    int*   Ca    = Cbase;
    int*   Cb    = Cbase + N;
    int*   Cp    = Cbase + 2 * N;                 // [4][M]
    float* stats = (float*)(Cbase + 2 * N + 4 * M);
    short* yslot = (short*)(base + oDyn);

    const size_t avail = (ws_size > oDyn) ? (ws_size - oDyn) : 0;
    long cA = (long)(avail / ((size_t)N * 128));
    long cP = (long)(avail / ((size_t)M * 128));
    const int capAB = (int)(cA < 12 ? cA : 12);   // LLC-sized window (154 MB at N=1e5)
    const int capP  = (int)(cP < 32 ? cP : 32);   // 102 MB at M=25e3

    dim3 blk(256);
    const int tilesPerK = (P + 15) / 16;
    const int TPW = 4;
    const int wavesPerK = (tilesPerK + TPW - 1) / TPW;
    auto nConvBlocks = [&](int nk) { return (nk * wavesPerK + 3) / 4; };
    auto gRowsR = [](int nr, int R) { return dim3((unsigned)((nr + 4 * R - 1) / (4 * R))); };
    auto rsvBlocks = [](int lo, int hi) { return (hi - lo + 2047) / 2048; };
    const int nx = N * 32, n1 = 9*32*64, n12 = 9*64*64, n2 = 9*32*64, n3 = 9*64*64, np = 27*64*64;
    const size_t fbytes = (size_t)N * 64 * sizeof(float);
    const int k1 = (Kp + 3) / 4, k2 = (2 * Kp + 3) / 4, k3 = (3 * Kp + 3) / 4;
    const int s1 = ((Ep / 3) / 2048) * 2048;
    const int s2 = ((2 * Ep / 3) / 2048) * 2048;

    hipMemsetAsync(Cbase, 0, ((size_t)2 * N + 4 * M + 512) * 4, stream);
    hipMemsetAsync(A0, 0, 2 * fbytes, stream);          // A0 + A1 (adjacent)
    hipMemsetAsync(d_out, 0, (size_t)out_size * 4, stream);   // resB + resA

    const bool slotPath = (capAB >= 8 && capP >= 24);
    const int CB = 1024;

    {
        const int rb = slotPath ? rsvBlocks(0, Ea) : 0;
        prep<<<dim3((unsigned)(CB + rb)), blk, 0, stream>>>(
            x, x_bf, nx,
            W1, W1b, W1f, slotPath ? 0 : n1,  slotPath ? f1  : 0,
            W12, W12b, W12f, slotPath ? 0 : n12, slotPath ? f12 : 0,
            W2, W2b, W2f, slotPath ? 0 : n2,  slotPath ? f2s : 0,
            W3, W3b, W3f, slotPath ? 0 : n3,  slotPath ? f3  : 0,
            Wp, Wpb, Wpf, slotPath ? 0 : np,  slotPath ? fp  : 0,
            CB, slotPath ? rb_a_out : nullptr, Ea, Ca, pos_a);
    }

    if (slotPath) {
        float* st0 = stats, *st1 = stats + 128, *st2 = stats + 256, *st3 = stats + 384;
        const int cb = nConvBlocks(Ka);

        // stage 1: conv1 (rb_a, x) -> A0 ; carries rb_b reserve
        spconv_slot<32, false><<<dim3((unsigned)(cb + rsvBlocks(0, Eb))), blk, 0, stream>>>(
            x_bf, W1f, rb_a_in, rb_a_out, pos_a, P, 0, Ka, tilesPerK, wavesPerK, TPW, capAB, yslot, A0,
            cb, rb_b_out, 0, Eb, Cb, pos_b, 1, M, 0, 0, 0);
        reduce_slot<false><<<gRowsR(N, 8), blk, 0, stream>>>(yslot, Ca, capAB, A0, N, 8, st0);
        bn_apply<<<512, blk, 0, stream>>>(A0, st0, g0, b0, t_bf, N, 1);   // zero A0 for stage 3

        // stage 2: conv1_2 (rb_b, t_bf) -> A1 (raw, BN deferred to apply4) ; pool 1/3
        spconv_slot<64, false><<<dim3((unsigned)(cb + rsvBlocks(0, s1))), blk, 0, stream>>>(
            t_bf, W12f, rb_b_in, rb_b_out, pos_b, P, 0, Ka, tilesPerK, wavesPerK, TPW, capAB, yslot, A1,
            cb, rb_p_out, 0, s1, Cp, pos_p, 2, M, k1, k2, k3);
        reduce_slot<false><<<gRowsR(N, 8), blk, 0, stream>>>(yslot, Cb, capAB, A1, N, 8, st1);

        // stage 3: conv2 (rb_b, x) -> A0 ; pool 2/3
        spconv_slot<32, false><<<dim3((unsigned)(cb + rsvBlocks(s1, s2))), blk, 0, stream>>>(
            x_bf, W2f, rb_b_in, rb_b_out, pos_b, P, 0, Ka, tilesPerK, wavesPerK, TPW, capAB, yslot, A0,
            cb, rb_p_out, s1, s2, Cp, pos_p, 2, M, k1, k2, k3);
        reduce_slot<false><<<gRowsR(N, 8), blk, 0, stream>>>(yslot, Cb, capAB, A0, N, 8, st2);
        bn_apply<<<512, blk, 0, stream>>>(A0, st2, g1, b1, t_bf, N, 0);

        // stage 4: conv3 (rb_a, t_bf) -> resA (true space) ; pool 3/3
        spconv_slot<64, true><<<dim3((unsigned)(cb + rsvBlocks(s2, Ep))), blk, 0, stream>>>(
            t_bf, W3f, rb_a_in, rb_a_out, pos_a, P, 0, Ka, tilesPerK, wavesPerK, TPW, capAB, yslot, resA,
            cb, rb_p_out, s2, Ep, Cp, pos_p, 2, M, k1, k2, k3);
        reduce_slot<true><<<gRowsR(N, 8), blk, 0, stream>>>(yslot, Ca, capAB, resA, N, 8, st3);

        // finalize resA (+shortcut) and pool input bf16 (t_bf)
        apply4<<<512, blk, 0, stream>>>(resA, st3, g2, b2, A1, st1, g02, b02, t_bf, N);

        // pool conv (rb_p, 64->64), 4 k-chunks -> resB (true)
        const int kc[5] = {0, k1, k2, k3, Kp};
        for (int c = 0; c < 4; ++c) {
            const int pcb = nConvBlocks(kc[c + 1] - kc[c]);
            spconv_slot<64, true><<<dim3((unsigned)pcb), blk, 0, stream>>>(
                t_bf, Wpf, rb_p_in, rb_p_out, pos_p, P, kc[c], kc[c + 1], tilesPerK, wavesPerK, TPW, capP, yslot, resB,
                pcb, nullptr, 0, 0, nullptr, nullptr, 0, 0, 0, 0, 0);
            reduce_slot<true><<<gRowsR(M, 2), blk, 0, stream>>>(yslot, Cp + c * M, capP, resB, M, 2, nullptr);
        }
    } else {
        // -------- atomic fallback --------
        const int TPW2 = 16;
        const int wPK = (tilesPerK + TPW2 - 1) / TPW2;
        auto cblocks = [&](int K) { return dim3((unsigned)((K * wPK + 3) / 4)); };
        float* st = stats;

        spconv_mfma<32><<<cblocks(Ka), blk, 0, stream>>>(x_bf, W1b, rb_a_in, rb_a_out, P, tilesPerK, wPK, Ka, TPW2, A0);
        bn_stats<<<256, blk, 0, stream>>>(A0, N, st);
        bn_apply_fb<<<512, blk, 0, stream>>>(A0, st, g0, b0, nullptr, t_bf, N);

        spconv_mfma<64><<<cblocks(Ka), blk, 0, stream>>>(t_bf, W12b, rb_b_in, rb_b_out, P, tilesPerK, wPK, Ka, TPW2, A1);
        bn_stats<<<256, blk, 0, stream>>>(A1, N, st + 128);
        bn_apply_fb<<<512, blk, 0, stream>>>(A1, st + 128, g02, b02, A1, nullptr, N);   // A1 = shortcut f32

        hipMemsetAsync(A0, 0, fbytes, stream);
        spconv_mfma<32><<<cblocks(Ka), blk, 0, stream>>>(x_bf, W2b, rb_b_in, rb_b_out, P, tilesPerK, wPK, Ka, TPW2, A0);
        bn_stats<<<256, blk, 0, stream>>>(A0, N, st + 256);
        bn_apply_fb<<<512, blk, 0, stream>>>(A0, st + 256, g1, b1, nullptr, t_bf, N);

        spconv_mfma<64><<<cblocks(Ka), blk, 0, stream>>>(t_bf, W3b, rb_a_in, rb_a_out, P, tilesPerK, wPK, Ka, TPW2, resA);
        bn_stats<<<256, blk, 0, stream>>>(resA, N, st + 384);
        bn_apply_fb<<<512, blk, 0, stream>>>(resA, st + 384, g2, b2, resA, nullptr, N);
        add_copy<<<512, blk, 0, stream>>>(resA, A1, t_bf, N);

        spconv_mfma<64><<<cblocks(Kp), blk, 0, stream>>>(t_bf, Wpb, rb_p_in, rb_p_out, P, tilesPerK, wPK, Kp, TPW2, resB);
    }
}

// Round 14
// 961.319 us; speedup vs baseline: 1.1556x; 1.1556x over previous
//
#include <hip/hip_runtime.h>

typedef __attribute__((ext_vector_type(8))) short short8;   // 8 x bf16
typedef __attribute__((ext_vector_type(4))) short short4v;  // 4 x bf16
typedef __attribute__((ext_vector_type(4))) float f32x4;

__device__ __forceinline__ float lrelu_f(float v) { return v > 0.f ? v : 0.01f * v; }
__device__ __forceinline__ short f2bf(float f) {
    unsigned u = __float_as_uint(f);
    return (short)((u + 0x7FFFu + ((u >> 16) & 1u)) >> 16);    // RNE
}
__device__ __forceinline__ float bf2f(unsigned short h) {
    return __uint_as_float(((unsigned)h) << 16);
}
// perm pos p = (c&15)*4 + (c>>4); p2t = inverse, t2p = forward
__device__ __forceinline__ int p2t(int p) { return ((p & 3) << 4) | (p >> 2); }
__device__ __forceinline__ int t2p(int c) { return ((c & 15) << 2) | (c >> 4); }

// weight fragment emit: dst layout ((k*4+ct)*KS+kk)*512 + lane*8 + r
__device__ __forceinline__ void emit_frag(const float* __restrict__ src, short* __restrict__ dst,
                                          int j, int KS, int permIn)
{
    int r = j & 7, lane = (j >> 3) & 63, rem = j >> 9;
    int kk = (KS == 2) ? (rem & 1) : 0;
    rem = (KS == 2) ? (rem >> 1) : rem;
    int ct = rem & 3, k = rem >> 2;
    int cinf = kk * 32 + ((lane >> 4) << 3) + r;
    int cin = permIn ? p2t(cinf) : cinf;
    int cout = ct * 16 + (lane & 15);
    int CIN = KS * 32;
    dst[j] = f2bf(src[(size_t)k * CIN * 64 + (size_t)cin * 64 + cout]);
}

// slot reservation worker (blocks of 2048 entries in [eLo,eHi))
__device__ __forceinline__ void do_reserve(
    const int* __restrict__ io, int eLo, int eHi,
    int* __restrict__ C, int* __restrict__ pos, int lb,
    int mode, int P, int M, int k1, int k2, int k3)
{
    const int e0 = eLo + lb * 2048 + (int)threadIdx.x * 8;
    if (e0 >= eHi) return;
    if (mode == 1 && e0 + 8 <= eHi) {
        int4 v0 = *(const int4*)(io + e0);
        int4 v1 = *(const int4*)(io + e0 + 4);
        int o[8] = {v0.x, v0.y, v0.z, v0.w, v1.x, v1.y, v1.z, v1.w};
        int p[8];
        #pragma unroll
        for (int j = 0; j < 8; ++j) p[j] = atomicAdd(&C[o[j]], 1);
        int4 r0 = {p[0], p[1], p[2], p[3]}, r1 = {p[4], p[5], p[6], p[7]};
        *(int4*)(pos + e0) = r0;
        *(int4*)(pos + e0 + 4) = r1;
    } else {
        for (int e = e0; e < eHi && e < e0 + 8; ++e) {
            int o = io[e];
            int* cp;
            if (mode == 2) {
                int k = e / P;
                int c = (k >= k3) ? 3 : (k >= k2) ? 2 : (k >= k1) ? 1 : 0;
                cp = &C[c * M + o];
            } else cp = &C[o];
            pos[e] = atomicAdd(cp, 1);
        }
    }
}

// converts (blocks < CB) + rb_a reservation (blocks >= CB)
__global__ __launch_bounds__(256) void prep(
    const float* __restrict__ x,  short* __restrict__ xb,  int nx,
    const float* __restrict__ W1, short* __restrict__ W1b,  short* __restrict__ W1f,  int n1,  int f1,
    const float* __restrict__ W12,short* __restrict__ W12b, short* __restrict__ W12f, int n12, int f12,
    const float* __restrict__ W2, short* __restrict__ W2b,  short* __restrict__ W2f,  int n2,  int f2,
    const float* __restrict__ W3, short* __restrict__ W3b,  short* __restrict__ W3f,  int n3,  int f3,
    const float* __restrict__ Wp, short* __restrict__ Wpb,  short* __restrict__ Wpf,  int np,  int fp,
    int CB,
    const int* __restrict__ ria, int rEa, int* __restrict__ rCa, int* __restrict__ rposA)
{
    if ((int)blockIdx.x >= CB) {
        if (ria) do_reserve(ria, 0, rEa, rCa, rposA, blockIdx.x - CB, 1, 0, 0, 0, 0, 0);
        return;
    }
    const int total = nx + n1 + n12 + n2 + n3 + np + f1 + f12 + f2 + f3 + fp;
    for (int i = blockIdx.x * 256 + threadIdx.x; i < total; i += CB * 256) {
        int j = i;
        if (j < nx)  { xb[j]   = f2bf(x[j]);   continue; } j -= nx;
        if (j < n1)  { W1b[j]  = f2bf(W1[j]);  continue; } j -= n1;
        if (j < n12) { W12b[j] = f2bf(W12[j]); continue; } j -= n12;
        if (j < n2)  { W2b[j]  = f2bf(W2[j]);  continue; } j -= n2;
        if (j < n3)  { W3b[j]  = f2bf(W3[j]);  continue; } j -= n3;
        if (j < np)  { Wpb[j]  = f2bf(Wp[j]);  continue; } j -= np;
        if (j < f1)  { emit_frag(W1,  W1f,  j, 1, 0); continue; } j -= f1;
        if (j < f12) { emit_frag(W12, W12f, j, 2, 1); continue; } j -= f12;
        if (j < f2)  { emit_frag(W2,  W2f,  j, 1, 0); continue; } j -= f2;
        if (j < f3)  { emit_frag(W3,  W3f,  j, 2, 1); continue; } j -= f3;
        emit_frag(Wp, Wpf, j, 2, 1);
    }
}

// slot-direct conv, batch-preloaded indices: each wave owns 64 entries
// (4 MFMA tiles); iin/iout/pos loaded once with full-wave coalesced loads and
// distributed via shfl; all 4 tiles' gathers issued before MFMA.
template<int CIN, bool OVF_TRUE>
__global__ __launch_bounds__(256) void spconv_slot(
    const short* __restrict__ feats,
    const short* __restrict__ Wf,
    const int*   __restrict__ iin,
    const int*   __restrict__ iout,
    const int*   __restrict__ pos,
    int P, int kLo, int kHi, int tilesPerK, int wavesPerK,
    int cap, short* __restrict__ yslot, float* __restrict__ outAcc,
    int convBlocks,
    const int* __restrict__ rio, int rLo, int rHi,
    int* __restrict__ rC, int* __restrict__ rpos,
    int rmode, int rM, int rk1, int rk2, int rk3)
{
    if ((int)blockIdx.x >= convBlocks) {
        if (rmode) do_reserve(rio, rLo, rHi, rC, rpos, blockIdx.x - convBlocks,
                              rmode, P, rM, rk1, rk2, rk3);
        return;
    }
    constexpr int KS = CIN / 32;
    const int lane = threadIdx.x & 63;
    int wid = blockIdx.x * 4 + (threadIdx.x >> 6);
    wid = __builtin_amdgcn_readfirstlane(wid);
    const int k = kLo + wid / wavesPerK;
    if (k >= kHi) return;
    const int wslot = wid % wavesPerK;
    const int t0 = wslot * 4;
    if (t0 >= tilesPerK) return;
    const int nt = (tilesPerK - t0 < 4) ? (tilesPerK - t0) : 4;
    const int kBase = k * P, kEnd = kBase + P;
    const int col = lane & 15, g = lane >> 4;

    // B fragments: coalesced 16B loads
    short8 bf[KS][4];
    const short* wkf = Wf + (size_t)k * 4 * KS * 512;
    #pragma unroll
    for (int ct = 0; ct < 4; ++ct)
        #pragma unroll
        for (int kk = 0; kk < KS; ++kk)
            bf[kk][ct] = *(const short8*)(wkf + ((size_t)(ct * KS + kk) << 9) + lane * 8);

    // batch preload of 64 entries' indices (full-wave coalesced)
    const int base64 = kBase + t0 * 16;
    const int e_l = base64 + lane;
    const int e_cl = (e_l < kEnd) ? e_l : kEnd - 1;
    const int iin_all = iin[e_cl];
    const int rr_all  = (e_l < kEnd) ? iout[e_l] : -1;
    const int pp_all  = (e_l < kEnd) ? pos[e_l] : 0;

    // issue all tiles' gathers up front
    short8 af[4][KS];
    #pragma unroll
    for (int tl = 0; tl < 4; ++tl) {
        if (tl >= nt) break;
        const int rin = __shfl(iin_all, tl * 16 + col);
        const short* fr = feats + (size_t)rin * CIN + g * 8;
        #pragma unroll
        for (int kk = 0; kk < KS; ++kk)
            af[tl][kk] = *(const short8*)(fr + kk * 32);
    }

    #pragma unroll
    for (int tl = 0; tl < 4; ++tl) {
        if (tl >= nt) break;
        const int base = base64 + tl * 16;
        f32x4 acc[4] = {f32x4{0,0,0,0}, f32x4{0,0,0,0}, f32x4{0,0,0,0}, f32x4{0,0,0,0}};
        #pragma unroll
        for (int kk = 0; kk < KS; ++kk)
            #pragma unroll
            for (int ct = 0; ct < 4; ++ct)
                acc[ct] = __builtin_amdgcn_mfma_f32_16x16x32_bf16(af[tl][kk], bf[kk][ct], acc[ct], 0, 0, 0);

        #pragma unroll
        for (int j = 0; j < 4; ++j) {
            const int er = base + g * 4 + j;
            const int r2 = __shfl(rr_all, tl * 16 + g * 4 + j);
            const int p2 = __shfl(pp_all, tl * 16 + g * 4 + j);
            if (er < kEnd && r2 >= 0) {
                if (p2 < cap) {
                    short4v v = { f2bf(acc[0][j]), f2bf(acc[1][j]), f2bf(acc[2][j]), f2bf(acc[3][j]) };
                    *(short4v*)(yslot + ((size_t)r2 * cap + p2) * 64 + col * 4) = v;
                } else {
                    float* op = outAcc + (size_t)r2 * 64;
                    #pragma unroll
                    for (int ct = 0; ct < 4; ++ct)
                        atomicAdd(op + (OVF_TRUE ? ct * 16 + col : col * 4 + ct), acc[ct][j]);
                }
            }
        }
    }
}

// slot-window reduce, ONE row per wave (max TLP); accumulates into out.
template<bool UNPERM>
__global__ __launch_bounds__(256) void reduce_slot(
    const short* __restrict__ yslot, const int* __restrict__ C, int cap,
    float* __restrict__ out, int nRows)
{
    const int lane = threadIdx.x & 63;
    const int r = blockIdx.x * 4 + (threadIdx.x >> 6);
    if (r >= nRows) return;
    int cnt = C[r]; if (cnt > cap) cnt = cap;
    const unsigned short* basep = (const unsigned short*)yslot + (size_t)r * cap * 64 + lane;
    float a0 = 0.f, a1 = 0.f, a2 = 0.f, a3 = 0.f;
    int s = 0;
    for (; s + 4 <= cnt; s += 4) {
        a0 += bf2f(basep[(s + 0) * 64]);
        a1 += bf2f(basep[(s + 1) * 64]);
        a2 += bf2f(basep[(s + 2) * 64]);
        a3 += bf2f(basep[(s + 3) * 64]);
    }
    for (; s < cnt; ++s) a0 += bf2f(basep[s * 64]);
    const int op_c = UNPERM ? p2t(lane) : lane;
    float* op = out + (size_t)r * 64 + op_c;
    *op = *op + ((a0 + a1) + (a2 + a3));
}

// per-position sum/sumsq of lrelu(A); stats pre-zeroed; index-space agnostic
__global__ __launch_bounds__(256) void bn_stats(
    const float* __restrict__ A, int n, float* __restrict__ stats)
{
    __shared__ float ls[256], lq[256];
    float s = 0.f, q = 0.f;
    const long total = (long)n * 64;
    const long stride = (long)gridDim.x * 256;
    for (long i = (long)blockIdx.x * 256 + threadIdx.x; i < total; i += stride) {
        float v = lrelu_f(A[i]);
        s += v; q += v * v;
    }
    ls[threadIdx.x] = s; lq[threadIdx.x] = q;
    __syncthreads();
    if (threadIdx.x < 64) {
        atomicAdd(&stats[threadIdx.x],
                  ls[threadIdx.x] + ls[threadIdx.x + 64] + ls[threadIdx.x + 128] + ls[threadIdx.x + 192]);
        atomicAdd(&stats[64 + threadIdx.x],
                  lq[threadIdx.x] + lq[threadIdx.x + 64] + lq[threadIdx.x + 128] + lq[threadIdx.x + 192]);
    }
}

// t_bf = bf16(bn(lrelu(A))) in perm space (A perm, stats perm-indexed);
// optionally zeroes A after read.
__global__ __launch_bounds__(256) void bn_apply(
    float* __restrict__ A, const float* __restrict__ stats,
    const float* __restrict__ gamma, const float* __restrict__ beta,
    short* __restrict__ out_bf, int n, int zeroA)
{
    const int c = threadIdx.x & 63;           // perm pos
    const float inv_n = 1.0f / (float)n;
    const float m   = stats[c] * inv_n;
    const float var = stats[64 + c] * inv_n - m * m;
    const float sc  = rsqrtf(var + 1e-5f) * gamma[p2t(c)];
    const float bb  = beta[p2t(c)] - m * sc;
    const long total = (long)n * 64;
    const long stride = (long)gridDim.x * blockDim.x;
    for (long i = (long)blockIdx.x * blockDim.x + threadIdx.x; i < total; i += stride) {
        float r = lrelu_f(A[i]) * sc + bb;
        out_bf[i] = f2bf(r);
        if (zeroA) A[i] = 0.f;
    }
}

// final: resA = bn3(lrelu(resA_raw)) + bn1(lrelu(A1)); writes perm bf16 copy.
// st3 TRUE-indexed (stats of resA, true space); st1 PERM-indexed (stats of A1).
__global__ __launch_bounds__(256) void apply4(
    float* __restrict__ resA, const float* __restrict__ st3,
    const float* __restrict__ g2, const float* __restrict__ b2,
    const float* __restrict__ A1, const float* __restrict__ st1,
    const float* __restrict__ g02, const float* __restrict__ b02,
    short* __restrict__ rA_bf, int n)
{
    const int tc = threadIdx.x & 63;          // true channel
    const int p  = t2p(tc);                   // perm pos
    const float inv_n = 1.0f / (float)n;
    float m3 = st3[tc] * inv_n, v3 = st3[64 + tc] * inv_n - m3 * m3;
    float sc3 = rsqrtf(v3 + 1e-5f) * g2[tc], bb3 = b2[tc] - m3 * sc3;
    float m1 = st1[p] * inv_n, v1 = st1[64 + p] * inv_n - m1 * m1;
    float sc1 = rsqrtf(v1 + 1e-5f) * g02[tc], bb1 = b02[tc] - m1 * sc1;
    const long total = (long)n * 64;
    const long stride = (long)gridDim.x * blockDim.x;
    for (long i = (long)blockIdx.x * blockDim.x + threadIdx.x; i < total; i += stride) {
        long row = i >> 6;
        float r3 = lrelu_f(resA[i]) * sc3 + bb3;
        float r1 = lrelu_f(A1[(row << 6) + p]) * sc1 + bb1;
        float out = r3 + r1;
        resA[i] = out;
        rA_bf[(row << 6) + p] = f2bf(out);
    }
}

// ---------------- fallback kernels (plain layouts) ----------------
template<int CIN>
__global__ __launch_bounds__(256) void spconv_mfma(
    const short* __restrict__ feats, const short* __restrict__ W,
    const int* __restrict__ iin, const int* __restrict__ iout,
    int P, int tilesPerK, int wavesPerK, int K, int TPW,
    float* __restrict__ out)
{
    constexpr int KS = CIN / 32;
    const int lane = threadIdx.x & 63;
    int wid = blockIdx.x * 4 + (threadIdx.x >> 6);
    wid = __builtin_amdgcn_readfirstlane(wid);
    const int k = wid / wavesPerK;
    if (k >= K) return;
    const int wslot = wid % wavesPerK;
    int t0 = wslot * TPW;
    if (t0 >= tilesPerK) return;
    const int t1 = (t0 + TPW < tilesPerK) ? t0 + TPW : tilesPerK;
    const int kBase = k * P, kEnd = kBase + P;
    const int col = lane & 15, g = lane >> 4;
    short8 bf[KS][4];
    const short* wk = W + (size_t)k * CIN * 64;
    #pragma unroll
    for (int kk = 0; kk < KS; ++kk)
        #pragma unroll
        for (int ct = 0; ct < 4; ++ct)
            #pragma unroll
            for (int r = 0; r < 8; ++r)
                bf[kk][ct][r] = wk[(size_t)(kk * 32 + g * 8 + r) * 64 + ct * 16 + col];
    for (int t = t0; t < t1; ++t) {
        const int base = kBase + t * 16;
        int ein = base + col;
        if (ein >= kEnd) ein = kEnd - 1;
        const int rin = iin[ein];
        short8 af[KS];
        const short* fr = feats + (size_t)rin * CIN + g * 8;
        #pragma unroll
        for (int kk = 0; kk < KS; ++kk)
            af[kk] = *(const short8*)(fr + kk * 32);
        f32x4 acc[4] = {f32x4{0,0,0,0}, f32x4{0,0,0,0}, f32x4{0,0,0,0}, f32x4{0,0,0,0}};
        #pragma unroll
        for (int kk = 0; kk < KS; ++kk)
            #pragma unroll
            for (int ct = 0; ct < 4; ++ct)
                acc[ct] = __builtin_amdgcn_mfma_f32_16x16x32_bf16(af[kk], bf[kk][ct], acc[ct], 0, 0, 0);
        const int rbase = base + g * 4;
        #pragma unroll
        for (int j = 0; j < 4; ++j) {
            const int er = rbase + j;
            if (er < kEnd) {
                const int rout = iout[er];
                float* op = out + (size_t)rout * 64 + col;
                #pragma unroll
                for (int ct = 0; ct < 4; ++ct)
                    atomicAdd(op + ct * 16, acc[ct][j]);
            }
        }
    }
}

__global__ __launch_bounds__(256) void bn_apply_fb(
    const float* __restrict__ A, const float* __restrict__ stats,
    const float* __restrict__ gamma, const float* __restrict__ beta,
    float* __restrict__ out_f32, short* __restrict__ out_bf, int n)
{
    const int c = threadIdx.x & 63;
    const float inv_n = 1.0f / (float)n;
    const float m   = stats[c] * inv_n;
    const float var = stats[64 + c] * inv_n - m * m;
    const float sc  = rsqrtf(var + 1e-5f) * gamma[c];
    const float bb  = beta[c] - m * sc;
    const long total = (long)n * 64;
    const long stride = (long)gridDim.x * blockDim.x;
    for (long i = (long)blockIdx.x * blockDim.x + threadIdx.x; i < total; i += stride) {
        float r = lrelu_f(A[i]) * sc + bb;
        if (out_f32) out_f32[i] = r;
        if (out_bf)  out_bf[i] = f2bf(r);
    }
}

__global__ __launch_bounds__(256) void add_copy(
    float* __restrict__ resA, const float* __restrict__ A1,
    short* __restrict__ t_bf, int n)
{
    const long total = (long)n * 64;
    const long stride = (long)gridDim.x * blockDim.x;
    for (long i = (long)blockIdx.x * blockDim.x + threadIdx.x; i < total; i += stride) {
        float v = resA[i] + A1[i];
        resA[i] = v;
        t_bf[i] = f2bf(v);
    }
}

extern "C" void kernel_launch(void* const* d_in, const int* in_sizes, int n_in,
                              void* d_out, int out_size, void* d_ws, size_t ws_size,
                              hipStream_t stream)
{
    const float* x   = (const float*)d_in[0];
    const float* W1  = (const float*)d_in[1];
    const float* W12 = (const float*)d_in[2];
    const float* W2  = (const float*)d_in[3];
    const float* W3  = (const float*)d_in[4];
    const float* Wp  = (const float*)d_in[5];
    const float* g0  = (const float*)d_in[6];
    const float* b0  = (const float*)d_in[7];
    const float* g02 = (const float*)d_in[8];
    const float* b02 = (const float*)d_in[9];
    const float* g1  = (const float*)d_in[10];
    const float* b1  = (const float*)d_in[11];
    const float* g2  = (const float*)d_in[12];
    const float* b2  = (const float*)d_in[13];
    const int* rb_a_in  = (const int*)d_in[14];
    const int* rb_a_out = (const int*)d_in[15];
    const int* rb_b_in  = (const int*)d_in[16];
    const int* rb_b_out = (const int*)d_in[17];
    const int* rb_p_in  = (const int*)d_in[18];
    const int* rb_p_out = (const int*)d_in[19];

    const int N  = in_sizes[0] / 32;
    const int M  = out_size / 64 - N;
    const int Ea = in_sizes[14];
    const int Eb = in_sizes[16];
    const int Ep = in_sizes[18];
    const int Ka = Ea / N, Kp = Ep / N;
    const int P  = N;

    float* resB = (float*)d_out;
    float* resA = resB + (size_t)M * 64;

    const int f1  = 9 * 4 * 1 * 512, f12 = 9 * 4 * 2 * 512;
    const int f2s = 9 * 4 * 1 * 512, f3  = 9 * 4 * 2 * 512, fp = 27 * 4 * 2 * 512;

    size_t off = 0;
    auto take = [&](size_t bytes) { size_t o = off; off += (bytes + 255) & ~(size_t)255; return o; };
    char* base = (char*)d_ws;
    size_t oA0   = take((size_t)N * 64 * 4);
    size_t oA1   = take((size_t)N * 64 * 4);
    size_t oSh   = take((size_t)N * 64 * 2);
    size_t oxb   = take((size_t)N * 32 * 2);
    size_t oW1   = take((size_t)9 * 32 * 64 * 2);
    size_t oW12  = take((size_t)9 * 64 * 64 * 2);
    size_t oW2   = take((size_t)9 * 32 * 64 * 2);
    size_t oW3   = take((size_t)9 * 64 * 64 * 2);
    size_t oWp   = take((size_t)27 * 64 * 64 * 2);
    size_t oW1f  = take((size_t)f1 * 2);
    size_t oW12f = take((size_t)f12 * 2);
    size_t oW2f  = take((size_t)f2s * 2);
    size_t oW3f  = take((size_t)f3 * 2);
    size_t oWpf  = take((size_t)fp * 2);
    size_t oPa   = take((size_t)Ea * 4);
    size_t oPb   = take((size_t)Eb * 4);
    size_t oPp   = take((size_t)Ep * 4);
    size_t oCNT  = take(((size_t)2 * N + 4 * M + 512) * 4);
    const size_t oDyn = off;

    float* A0    = (float*)(base + oA0);
    float* A1    = (float*)(base + oA1);
    short* t_bf  = (short*)(base + oSh);
    short* x_bf  = (short*)(base + oxb);
    short* W1b   = (short*)(base + oW1);
    short* W12b  = (short*)(base + oW12);
    short* W2b   = (short*)(base + oW2);
    short* W3b   = (short*)(base + oW3);
    short* Wpb   = (short*)(base + oWp);
    short* W1f   = (short*)(base + oW1f);
    short* W12f  = (short*)(base + oW12f);
    short* W2f   = (short*)(base + oW2f);
    short* W3f   = (short*)(base + oW3f);
    short* Wpf   = (short*)(base + oWpf);
    int*   pos_a = (int*)(base + oPa);
    int*   pos_b = (int*)(base + oPb);
    int*   pos_p = (int*)(base + oPp);
    int*   Cbase = (int*)(base + oCNT);
    int*   Ca    = Cbase;
    int*   Cb    = Cbase + N;
    int*   Cp    = Cbase + 2 * N;                 // [4][M]
    float* stats = (float*)(Cbase + 2 * N + 4 * M);
    short* yslot = (short*)(base + oDyn);

    const size_t avail = (ws_size > oDyn) ? (ws_size - oDyn) : 0;
    long cA = (long)(avail / ((size_t)N * 128));
    long cP = (long)(avail / ((size_t)M * 128));
    const int capAB = (int)(cA < 16 ? cA : 16);
    const int capP  = (int)(cP < 40 ? cP : 40);

    dim3 blk(256);
    const int tilesPerK = (P + 15) / 16;
    const int wavesPerK = (tilesPerK + 3) / 4;    // 4 tiles (=64 entries) per wave
    auto nConvBlocks = [&](int nk) { return (nk * wavesPerK + 3) / 4; };
    auto gRows  = [](int nr) { return dim3((unsigned)((nr + 3) / 4)); };
    auto rsvBlocks = [](int lo, int hi) { return (hi - lo + 2047) / 2048; };
    const int nx = N * 32, n1 = 9*32*64, n12 = 9*64*64, n2 = 9*32*64, n3 = 9*64*64, np = 27*64*64;
    const size_t fbytes = (size_t)N * 64 * sizeof(float);
    const int k1 = (Kp + 3) / 4, k2 = (2 * Kp + 3) / 4, k3 = (3 * Kp + 3) / 4;
    const int s1 = ((Ep / 3) / 2048) * 2048;
    const int s2 = ((2 * Ep / 3) / 2048) * 2048;

    hipMemsetAsync(Cbase, 0, ((size_t)2 * N + 4 * M + 512) * 4, stream);
    hipMemsetAsync(A0, 0, 2 * fbytes, stream);                 // A0 + A1
    hipMemsetAsync(d_out, 0, (size_t)out_size * 4, stream);    // resB + resA

    const bool slotPath = (capAB >= 8 && capP >= 24);
    const int CB = 1024;

    {
        const int rb = slotPath ? rsvBlocks(0, Ea) : 0;
        prep<<<dim3((unsigned)(CB + rb)), blk, 0, stream>>>(
            x, x_bf, nx,
            W1, W1b, W1f, slotPath ? 0 : n1,  slotPath ? f1  : 0,
            W12, W12b, W12f, slotPath ? 0 : n12, slotPath ? f12 : 0,
            W2, W2b, W2f, slotPath ? 0 : n2,  slotPath ? f2s : 0,
            W3, W3b, W3f, slotPath ? 0 : n3,  slotPath ? f3  : 0,
            Wp, Wpb, Wpf, slotPath ? 0 : np,  slotPath ? fp  : 0,
            CB, slotPath ? rb_a_out : nullptr, Ea, Ca, pos_a);
    }

    if (slotPath) {
        float* st0 = stats, *st1 = stats + 128, *st2 = stats + 256, *st3 = stats + 384;
        const int cb = nConvBlocks(Ka);

        // stage 1: conv1 (rb_a, x) -> A0 ; carries rb_b reserve
        spconv_slot<32, false><<<dim3((unsigned)(cb + rsvBlocks(0, Eb))), blk, 0, stream>>>(
            x_bf, W1f, rb_a_in, rb_a_out, pos_a, P, 0, Ka, tilesPerK, wavesPerK, capAB, yslot, A0,
            cb, rb_b_out, 0, Eb, Cb, pos_b, 1, M, 0, 0, 0);
        reduce_slot<false><<<gRows(N), blk, 0, stream>>>(yslot, Ca, capAB, A0, N);
        bn_stats<<<256, blk, 0, stream>>>(A0, N, st0);
        bn_apply<<<512, blk, 0, stream>>>(A0, st0, g0, b0, t_bf, N, 1);   // zero A0 for stage 3

        // stage 2: conv1_2 (rb_b, t_bf) -> A1 raw (BN deferred) ; pool 1/3
        spconv_slot<64, false><<<dim3((unsigned)(cb + rsvBlocks(0, s1))), blk, 0, stream>>>(
            t_bf, W12f, rb_b_in, rb_b_out, pos_b, P, 0, Ka, tilesPerK, wavesPerK, capAB, yslot, A1,
            cb, rb_p_out, 0, s1, Cp, pos_p, 2, M, k1, k2, k3);
        reduce_slot<false><<<gRows(N), blk, 0, stream>>>(yslot, Cb, capAB, A1, N);
        bn_stats<<<256, blk, 0, stream>>>(A1, N, st1);

        // stage 3: conv2 (rb_b, x) -> A0 ; pool 2/3
        spconv_slot<32, false><<<dim3((unsigned)(cb + rsvBlocks(s1, s2))), blk, 0, stream>>>(
            x_bf, W2f, rb_b_in, rb_b_out, pos_b, P, 0, Ka, tilesPerK, wavesPerK, capAB, yslot, A0,
            cb, rb_p_out, s1, s2, Cp, pos_p, 2, M, k1, k2, k3);
        reduce_slot<false><<<gRows(N), blk, 0, stream>>>(yslot, Cb, capAB, A0, N);
        bn_stats<<<256, blk, 0, stream>>>(A0, N, st2);
        bn_apply<<<512, blk, 0, stream>>>(A0, st2, g1, b1, t_bf, N, 0);

        // stage 4: conv3 (rb_a, t_bf) -> resA (true) ; pool 3/3
        spconv_slot<64, true><<<dim3((unsigned)(cb + rsvBlocks(s2, Ep))), blk, 0, stream>>>(
            t_bf, W3f, rb_a_in, rb_a_out, pos_a, P, 0, Ka, tilesPerK, wavesPerK, capAB, yslot, resA,
            cb, rb_p_out, s2, Ep, Cp, pos_p, 2, M, k1, k2, k3);
        reduce_slot<true><<<gRows(N), blk, 0, stream>>>(yslot, Ca, capAB, resA, N);
        bn_stats<<<256, blk, 0, stream>>>(resA, N, st3);          // TRUE-indexed

        apply4<<<512, blk, 0, stream>>>(resA, st3, g2, b2, A1, st1, g02, b02, t_bf, N);

        // pool conv (rb_p), 4 k-chunks -> resB (true)
        const int kc[5] = {0, k1, k2, k3, Kp};
        for (int c = 0; c < 4; ++c) {
            const int pcb = nConvBlocks(kc[c + 1] - kc[c]);
            spconv_slot<64, true><<<dim3((unsigned)pcb), blk, 0, stream>>>(
                t_bf, Wpf, rb_p_in, rb_p_out, pos_p, P, kc[c], kc[c + 1], tilesPerK, wavesPerK, capP, yslot, resB,
                pcb, nullptr, 0, 0, nullptr, nullptr, 0, 0, 0, 0, 0);
            reduce_slot<true><<<gRows(M), blk, 0, stream>>>(yslot, Cp + c * M, capP, resB, M);
        }
    } else {
        // -------- atomic fallback --------
        const int TPW2 = 16;
        const int wPK = (tilesPerK + TPW2 - 1) / TPW2;
        auto cblocks = [&](int K) { return dim3((unsigned)((K * wPK + 3) / 4)); };
        float* st = stats;

        spconv_mfma<32><<<cblocks(Ka), blk, 0, stream>>>(x_bf, W1b, rb_a_in, rb_a_out, P, tilesPerK, wPK, Ka, TPW2, A0);
        bn_stats<<<256, blk, 0, stream>>>(A0, N, st);
        bn_apply_fb<<<512, blk, 0, stream>>>(A0, st, g0, b0, nullptr, t_bf, N);

        spconv_mfma<64><<<cblocks(Ka), blk, 0, stream>>>(t_bf, W12b, rb_b_in, rb_b_out, P, tilesPerK, wPK, Ka, TPW2, A1);
        bn_stats<<<256, blk, 0, stream>>>(A1, N, st + 128);
        bn_apply_fb<<<512, blk, 0, stream>>>(A1, st + 128, g02, b02, A1, nullptr, N);

        hipMemsetAsync(A0, 0, fbytes, stream);
        spconv_mfma<32><<<cblocks(Ka), blk, 0, stream>>>(x_bf, W2b, rb_b_in, rb_b_out, P, tilesPerK, wPK, Ka, TPW2, A0);
        bn_stats<<<256, blk, 0, stream>>>(A0, N, st + 256);
        bn_apply_fb<<<512, blk, 0, stream>>>(A0, st + 256, g1, b1, nullptr, t_bf, N);

        spconv_mfma<64><<<cblocks(Ka), blk, 0, stream>>>(t_bf, W3b, rb_a_in, rb_a_out, P, tilesPerK, wPK, Ka, TPW2, resA);
        bn_stats<<<256, blk, 0, stream>>>(resA, N, st + 384);
        bn_apply_fb<<<512, blk, 0, stream>>>(resA, st + 384, g2, b2, resA, nullptr, N);
        add_copy<<<512, blk, 0, stream>>>(resA, A1, t_bf, N);

        spconv_mfma<64><<<cblocks(Kp), blk, 0, stream>>>(t_bf, Wpb, rb_p_in, rb_p_out, P, tilesPerK, wPK, Kp, TPW2, resB);
    }
}

// Round 15
// 916.241 us; speedup vs baseline: 1.2124x; 1.0492x over previous
//
#include <hip/hip_runtime.h>

typedef __attribute__((ext_vector_type(8))) short short8;   // 8 x bf16
typedef __attribute__((ext_vector_type(4))) short short4v;  // 4 x bf16
typedef __attribute__((ext_vector_type(4))) float f32x4;

__device__ __forceinline__ float lrelu_f(float v) { return v > 0.f ? v : 0.01f * v; }
__device__ __forceinline__ short f2bf(float f) {
    unsigned u = __float_as_uint(f);
    return (short)((u + 0x7FFFu + ((u >> 16) & 1u)) >> 16);    // RNE
}
__device__ __forceinline__ float bf2f(unsigned short h) {
    return __uint_as_float(((unsigned)h) << 16);
}
// perm pos p = (c&15)*4 + (c>>4); p2t = inverse, t2p = forward
__device__ __forceinline__ int p2t(int p) { return ((p & 3) << 4) | (p >> 2); }
__device__ __forceinline__ int t2p(int c) { return ((c & 15) << 2) | (c >> 4); }

// weight fragment emit: dst layout ((k*4+ct)*KS+kk)*512 + lane*8 + r
__device__ __forceinline__ void emit_frag(const float* __restrict__ src, short* __restrict__ dst,
                                          int j, int KS, int permIn)
{
    int r = j & 7, lane = (j >> 3) & 63, rem = j >> 9;
    int kk = (KS == 2) ? (rem & 1) : 0;
    rem = (KS == 2) ? (rem >> 1) : rem;
    int ct = rem & 3, k = rem >> 2;
    int cinf = kk * 32 + ((lane >> 4) << 3) + r;
    int cin = permIn ? p2t(cinf) : cinf;
    int cout = ct * 16 + (lane & 15);
    int CIN = KS * 32;
    dst[j] = f2bf(src[(size_t)k * CIN * 64 + (size_t)cin * 64 + cout]);
}

// slot reservation worker (blocks of 2048 entries in [eLo,eHi))
__device__ __forceinline__ void do_reserve(
    const int* __restrict__ io, int eLo, int eHi,
    int* __restrict__ C, int* __restrict__ pos, int lb,
    int mode, int P, int M, int k1, int k2, int k3)
{
    const int e0 = eLo + lb * 2048 + (int)threadIdx.x * 8;
    if (e0 >= eHi) return;
    if (mode == 1 && e0 + 8 <= eHi) {
        int4 v0 = *(const int4*)(io + e0);
        int4 v1 = *(const int4*)(io + e0 + 4);
        int o[8] = {v0.x, v0.y, v0.z, v0.w, v1.x, v1.y, v1.z, v1.w};
        int p[8];
        #pragma unroll
        for (int j = 0; j < 8; ++j) p[j] = atomicAdd(&C[o[j]], 1);
        int4 r0 = {p[0], p[1], p[2], p[3]}, r1 = {p[4], p[5], p[6], p[7]};
        *(int4*)(pos + e0) = r0;
        *(int4*)(pos + e0 + 4) = r1;
    } else {
        for (int e = e0; e < eHi && e < e0 + 8; ++e) {
            int o = io[e];
            int* cp;
            if (mode == 2) {
                int k = e / P;
                int c = (k >= k3) ? 3 : (k >= k2) ? 2 : (k >= k1) ? 1 : 0;
                cp = &C[c * M + o];
            } else cp = &C[o];
            pos[e] = atomicAdd(cp, 1);
        }
    }
}

// converts (blocks < CB) + rb_a reservation + rb_b reservation
__global__ __launch_bounds__(256) void prep(
    const float* __restrict__ x,  short* __restrict__ xb,  int nx,
    const float* __restrict__ W1, short* __restrict__ W1b,  short* __restrict__ W1f,  int n1,  int f1,
    const float* __restrict__ W12,short* __restrict__ W12b, short* __restrict__ W12f, int n12, int f12,
    const float* __restrict__ W2, short* __restrict__ W2b,  short* __restrict__ W2f,  int n2,  int f2,
    const float* __restrict__ W3, short* __restrict__ W3b,  short* __restrict__ W3f,  int n3,  int f3,
    const float* __restrict__ Wp, short* __restrict__ Wpb,  short* __restrict__ Wpf,  int np,  int fp,
    int CB,
    const int* __restrict__ ria, int rEa, int* __restrict__ rCa, int* __restrict__ rposA, int rbA,
    const int* __restrict__ rib, int rEb, int* __restrict__ rCb, int* __restrict__ rposB)
{
    if ((int)blockIdx.x >= CB) {
        const int b = blockIdx.x - CB;
        if (ria) {
            if (b < rbA) do_reserve(ria, 0, rEa, rCa, rposA, b, 1, 0, 0, 0, 0, 0);
            else         do_reserve(rib, 0, rEb, rCb, rposB, b - rbA, 1, 0, 0, 0, 0, 0);
        }
        return;
    }
    const int total = nx + n1 + n12 + n2 + n3 + np + f1 + f12 + f2 + f3 + fp;
    for (int i = blockIdx.x * 256 + threadIdx.x; i < total; i += CB * 256) {
        int j = i;
        if (j < nx)  { xb[j]   = f2bf(x[j]);   continue; } j -= nx;
        if (j < n1)  { W1b[j]  = f2bf(W1[j]);  continue; } j -= n1;
        if (j < n12) { W12b[j] = f2bf(W12[j]); continue; } j -= n12;
        if (j < n2)  { W2b[j]  = f2bf(W2[j]);  continue; } j -= n2;
        if (j < n3)  { W3b[j]  = f2bf(W3[j]);  continue; } j -= n3;
        if (j < np)  { Wpb[j]  = f2bf(Wp[j]);  continue; } j -= np;
        if (j < f1)  { emit_frag(W1,  W1f,  j, 1, 0); continue; } j -= f1;
        if (j < f12) { emit_frag(W12, W12f, j, 2, 1); continue; } j -= f12;
        if (j < f2)  { emit_frag(W2,  W2f,  j, 1, 0); continue; } j -= f2;
        if (j < f3)  { emit_frag(W3,  W3f,  j, 2, 1); continue; } j -= f3;
        emit_frag(Wp, Wpf, j, 2, 1);
    }
}

// slot-direct conv (lean r11 shape); piggybacked reservation on tail blocks.
template<int CIN, bool OVF_TRUE>
__global__ __launch_bounds__(256) void spconv_slot(
    const short* __restrict__ feats,
    const short* __restrict__ Wf,
    const int*   __restrict__ iin,
    const int*   __restrict__ iout,
    const int*   __restrict__ pos,
    int P, int kLo, int kHi, int tilesPerK, int wavesPerK, int TPW,
    int cap, short* __restrict__ yslot, float* __restrict__ outAcc,
    int convBlocks,
    const int* __restrict__ rio, int rLo, int rHi,
    int* __restrict__ rC, int* __restrict__ rpos,
    int rmode, int rM, int rk1, int rk2, int rk3)
{
    if ((int)blockIdx.x >= convBlocks) {
        if (rmode) do_reserve(rio, rLo, rHi, rC, rpos, blockIdx.x - convBlocks,
                              rmode, P, rM, rk1, rk2, rk3);
        return;
    }
    constexpr int KS = CIN / 32;
    const int lane = threadIdx.x & 63;
    int wid = blockIdx.x * 4 + (threadIdx.x >> 6);
    wid = __builtin_amdgcn_readfirstlane(wid);
    const int k = kLo + wid / wavesPerK;
    if (k >= kHi) return;
    const int wslot = wid % wavesPerK;
    int t0 = wslot * TPW;
    if (t0 >= tilesPerK) return;
    const int t1 = (t0 + TPW < tilesPerK) ? t0 + TPW : tilesPerK;
    const int kBase = k * P, kEnd = kBase + P;
    const int col = lane & 15, g = lane >> 4;

    short8 bf[KS][4];
    const short* wkf = Wf + (size_t)k * 4 * KS * 512;
    #pragma unroll
    for (int ct = 0; ct < 4; ++ct)
        #pragma unroll
        for (int kk = 0; kk < KS; ++kk)
            bf[kk][ct] = *(const short8*)(wkf + ((size_t)(ct * KS + kk) << 9) + lane * 8);

    for (int t = t0; t < t1; ++t) {
        const int base = kBase + t * 16;
        int rr = -1, pp = 0;
        if (lane < 16) {
            int ee = base + lane;
            if (ee < kEnd) { rr = iout[ee]; pp = pos[ee]; }
        }
        int ein = base + col;
        if (ein >= kEnd) ein = kEnd - 1;
        const int rin = iin[ein];
        short8 af[KS];
        const short* fr = feats + (size_t)rin * CIN + g * 8;
        #pragma unroll
        for (int kk = 0; kk < KS; ++kk)
            af[kk] = *(const short8*)(fr + kk * 32);

        f32x4 acc[4] = {f32x4{0,0,0,0}, f32x4{0,0,0,0}, f32x4{0,0,0,0}, f32x4{0,0,0,0}};
        #pragma unroll
        for (int kk = 0; kk < KS; ++kk)
            #pragma unroll
            for (int ct = 0; ct < 4; ++ct)
                acc[ct] = __builtin_amdgcn_mfma_f32_16x16x32_bf16(af[kk], bf[kk][ct], acc[ct], 0, 0, 0);

        #pragma unroll
        for (int j = 0; j < 4; ++j) {
            const int er = base + g * 4 + j;
            const int r2 = __shfl(rr, g * 4 + j);
            const int p2 = __shfl(pp, g * 4 + j);
            if (er < kEnd && r2 >= 0) {
                if (p2 < cap) {
                    short4v v = { f2bf(acc[0][j]), f2bf(acc[1][j]), f2bf(acc[2][j]), f2bf(acc[3][j]) };
                    *(short4v*)(yslot + ((size_t)r2 * cap + p2) * 64 + col * 4) = v;
                } else {
                    float* op = outAcc + (size_t)r2 * 64;
                    #pragma unroll
                    for (int ct = 0; ct < 4; ++ct)
                        atomicAdd(op + (OVF_TRUE ? ct * 16 + col : col * 4 + ct), acc[ct][j]);
                }
            }
        }
    }
}

// slot-window reduce, one row per wave. Reads prior value only if accumulating
// (later pool chunk) or the row overflowed (atomics landed in out).
template<bool UNPERM>
__global__ __launch_bounds__(256) void reduce_slot(
    const short* __restrict__ yslot, const int* __restrict__ C, int cap,
    float* __restrict__ out, int nRows, int accumulate)
{
    const int lane = threadIdx.x & 63;
    const int r = blockIdx.x * 4 + (threadIdx.x >> 6);
    if (r >= nRows) return;
    const int craw = C[r];
    const int cnt = (craw > cap) ? cap : craw;
    const unsigned short* basep = (const unsigned short*)yslot + (size_t)r * cap * 64 + lane;
    float a0 = 0.f, a1 = 0.f, a2 = 0.f, a3 = 0.f;
    int s = 0;
    for (; s + 4 <= cnt; s += 4) {
        a0 += bf2f(basep[(s + 0) * 64]);
        a1 += bf2f(basep[(s + 1) * 64]);
        a2 += bf2f(basep[(s + 2) * 64]);
        a3 += bf2f(basep[(s + 3) * 64]);
    }
    for (; s < cnt; ++s) a0 += bf2f(basep[s * 64]);
    const int op_c = UNPERM ? p2t(lane) : lane;
    float* op = out + (size_t)r * 64 + op_c;
    float init = (accumulate || craw > cap) ? *op : 0.f;
    *op = init + ((a0 + a1) + (a2 + a3));
}

// per-position sum/sumsq of lrelu(A); stats pre-zeroed
__global__ __launch_bounds__(256) void bn_stats(
    const float* __restrict__ A, int n, float* __restrict__ stats)
{
    __shared__ float ls[256], lq[256];
    float s = 0.f, q = 0.f;
    const long total = (long)n * 64;
    const long stride = (long)gridDim.x * 256;
    for (long i = (long)blockIdx.x * 256 + threadIdx.x; i < total; i += stride) {
        float v = lrelu_f(A[i]);
        s += v; q += v * v;
    }
    ls[threadIdx.x] = s; lq[threadIdx.x] = q;
    __syncthreads();
    if (threadIdx.x < 64) {
        atomicAdd(&stats[threadIdx.x],
                  ls[threadIdx.x] + ls[threadIdx.x + 64] + ls[threadIdx.x + 128] + ls[threadIdx.x + 192]);
        atomicAdd(&stats[64 + threadIdx.x],
                  lq[threadIdx.x] + lq[threadIdx.x + 64] + lq[threadIdx.x + 128] + lq[threadIdx.x + 192]);
    }
}

// t_bf = bf16(bn(lrelu(A))) in perm space; optionally zeroes A after read.
__global__ __launch_bounds__(256) void bn_apply(
    float* __restrict__ A, const float* __restrict__ stats,
    const float* __restrict__ gamma, const float* __restrict__ beta,
    short* __restrict__ out_bf, int n, int zeroA)
{
    const int c = threadIdx.x & 63;           // perm pos
    const float inv_n = 1.0f / (float)n;
    const float m   = stats[c] * inv_n;
    const float var = stats[64 + c] * inv_n - m * m;
    const float sc  = rsqrtf(var + 1e-5f) * gamma[p2t(c)];
    const float bb  = beta[p2t(c)] - m * sc;
    const long total = (long)n * 64;
    const long stride = (long)gridDim.x * blockDim.x;
    for (long i = (long)blockIdx.x * blockDim.x + threadIdx.x; i < total; i += stride) {
        float r = lrelu_f(A[i]) * sc + bb;
        out_bf[i] = f2bf(r);
        if (zeroA) A[i] = 0.f;
    }
}

// final: resA = bn3(lrelu(resA_raw)) + bn1(lrelu(A1)); writes perm bf16 copy.
// st3 TRUE-indexed; st1 PERM-indexed.
__global__ __launch_bounds__(256) void apply4(
    float* __restrict__ resA, const float* __restrict__ st3,
    const float* __restrict__ g2, const float* __restrict__ b2,
    const float* __restrict__ A1, const float* __restrict__ st1,
    const float* __restrict__ g02, const float* __restrict__ b02,
    short* __restrict__ rA_bf, int n)
{
    const int tc = threadIdx.x & 63;          // true channel
    const int p  = t2p(tc);                   // perm pos
    const float inv_n = 1.0f / (float)n;
    float m3 = st3[tc] * inv_n, v3 = st3[64 + tc] * inv_n - m3 * m3;
    float sc3 = rsqrtf(v3 + 1e-5f) * g2[tc], bb3 = b2[tc] - m3 * sc3;
    float m1 = st1[p] * inv_n, v1 = st1[64 + p] * inv_n - m1 * m1;
    float sc1 = rsqrtf(v1 + 1e-5f) * g02[tc], bb1 = b02[tc] - m1 * sc1;
    const long total = (long)n * 64;
    const long stride = (long)gridDim.x * blockDim.x;
    for (long i = (long)blockIdx.x * blockDim.x + threadIdx.x; i < total; i += stride) {
        long row = i >> 6;
        float r3 = lrelu_f(resA[i]) * sc3 + bb3;
        float r1 = lrelu_f(A1[(row << 6) + p]) * sc1 + bb1;
        float out = r3 + r1;
        resA[i] = out;
        rA_bf[(row << 6) + p] = f2bf(out);
    }
}

// ---------------- fallback kernels (plain layouts) ----------------
template<int CIN>
__global__ __launch_bounds__(256) void spconv_mfma(
    const short* __restrict__ feats, const short* __restrict__ W,
    const int* __restrict__ iin, const int* __restrict__ iout,
    int P, int tilesPerK, int wavesPerK, int K, int TPW,
    float* __restrict__ out)
{
    constexpr int KS = CIN / 32;
    const int lane = threadIdx.x & 63;
    int wid = blockIdx.x * 4 + (threadIdx.x >> 6);
    wid = __builtin_amdgcn_readfirstlane(wid);
    const int k = wid / wavesPerK;
    if (k >= K) return;
    const int wslot = wid % wavesPerK;
    int t0 = wslot * TPW;
    if (t0 >= tilesPerK) return;
    const int t1 = (t0 + TPW < tilesPerK) ? t0 + TPW : tilesPerK;
    const int kBase = k * P, kEnd = kBase + P;
    const int col = lane & 15, g = lane >> 4;
    short8 bf[KS][4];
    const short* wk = W + (size_t)k * CIN * 64;
    #pragma unroll
    for (int kk = 0; kk < KS; ++kk)
        #pragma unroll
        for (int ct = 0; ct < 4; ++ct)
            #pragma unroll
            for (int r = 0; r < 8; ++r)
                bf[kk][ct][r] = wk[(size_t)(kk * 32 + g * 8 + r) * 64 + ct * 16 + col];
    for (int t = t0; t < t1; ++t) {
        const int base = kBase + t * 16;
        int ein = base + col;
        if (ein >= kEnd) ein = kEnd - 1;
        const int rin = iin[ein];
        short8 af[KS];
        const short* fr = feats + (size_t)rin * CIN + g * 8;
        #pragma unroll
        for (int kk = 0; kk < KS; ++kk)
            af[kk] = *(const short8*)(fr + kk * 32);
        f32x4 acc[4] = {f32x4{0,0,0,0}, f32x4{0,0,0,0}, f32x4{0,0,0,0}, f32x4{0,0,0,0}};
        #pragma unroll
        for (int kk = 0; kk < KS; ++kk)
            #pragma unroll
            for (int ct = 0; ct < 4; ++ct)
                acc[ct] = __builtin_amdgcn_mfma_f32_16x16x32_bf16(af[kk], bf[kk][ct], acc[ct], 0, 0, 0);
        const int rbase = base + g * 4;
        #pragma unroll
        for (int j = 0; j < 4; ++j) {
            const int er = rbase + j;
            if (er < kEnd) {
                const int rout = iout[er];
                float* op = out + (size_t)rout * 64 + col;
                #pragma unroll
                for (int ct = 0; ct < 4; ++ct)
                    atomicAdd(op + ct * 16, acc[ct][j]);
            }
        }
    }
}

__global__ __launch_bounds__(256) void bn_apply_fb(
    const float* __restrict__ A, const float* __restrict__ stats,
    const float* __restrict__ gamma, const float* __restrict__ beta,
    float* __restrict__ out_f32, short* __restrict__ out_bf, int n)
{
    const int c = threadIdx.x & 63;
    const float inv_n = 1.0f / (float)n;
    const float m   = stats[c] * inv_n;
    const float var = stats[64 + c] * inv_n - m * m;
    const float sc  = rsqrtf(var + 1e-5f) * gamma[c];
    const float bb  = beta[c] - m * sc;
    const long total = (long)n * 64;
    const long stride = (long)gridDim.x * blockDim.x;
    for (long i = (long)blockIdx.x * blockDim.x + threadIdx.x; i < total; i += stride) {
        float r = lrelu_f(A[i]) * sc + bb;
        if (out_f32) out_f32[i] = r;
        if (out_bf)  out_bf[i] = f2bf(r);
    }
}

__global__ __launch_bounds__(256) void add_copy(
    float* __restrict__ resA, const float* __restrict__ A1,
    short* __restrict__ t_bf, int n)
{
    const long total = (long)n * 64;
    const long stride = (long)gridDim.x * blockDim.x;
    for (long i = (long)blockIdx.x * blockDim.x + threadIdx.x; i < total; i += stride) {
        float v = resA[i] + A1[i];
        resA[i] = v;
        t_bf[i] = f2bf(v);
    }
}

extern "C" void kernel_launch(void* const* d_in, const int* in_sizes, int n_in,
                              void* d_out, int out_size, void* d_ws, size_t ws_size,
                              hipStream_t stream)
{
    const float* x   = (const float*)d_in[0];
    const float* W1  = (const float*)d_in[1];
    const float* W12 = (const float*)d_in[2];
    const float* W2  = (const float*)d_in[3];
    const float* W3  = (const float*)d_in[4];
    const float* Wp  = (const float*)d_in[5];
    const float* g0  = (const float*)d_in[6];
    const float* b0  = (const float*)d_in[7];
    const float* g02 = (const float*)d_in[8];
    const float* b02 = (const float*)d_in[9];
    const float* g1  = (const float*)d_in[10];
    const float* b1  = (const float*)d_in[11];
    const float* g2  = (const float*)d_in[12];
    const float* b2  = (const float*)d_in[13];
    const int* rb_a_in  = (const int*)d_in[14];
    const int* rb_a_out = (const int*)d_in[15];
    const int* rb_b_in  = (const int*)d_in[16];
    const int* rb_b_out = (const int*)d_in[17];
    const int* rb_p_in  = (const int*)d_in[18];
    const int* rb_p_out = (const int*)d_in[19];

    const int N  = in_sizes[0] / 32;
    const int M  = out_size / 64 - N;
    const int Ea = in_sizes[14];
    const int Eb = in_sizes[16];
    const int Ep = in_sizes[18];
    const int Ka = Ea / N, Kp = Ep / N;
    const int P  = N;

    float* resB = (float*)d_out;
    float* resA = resB + (size_t)M * 64;

    const int f1  = 9 * 4 * 1 * 512, f12 = 9 * 4 * 2 * 512;
    const int f2s = 9 * 4 * 1 * 512, f3  = 9 * 4 * 2 * 512, fp = 27 * 4 * 2 * 512;

    size_t off = 0;
    auto take = [&](size_t bytes) { size_t o = off; off += (bytes + 255) & ~(size_t)255; return o; };
    char* base = (char*)d_ws;
    size_t oA0   = take((size_t)N * 64 * 4);
    size_t oA1   = take((size_t)N * 64 * 4);
    size_t oSh   = take((size_t)N * 64 * 2);
    size_t oxb   = take((size_t)N * 32 * 2);
    size_t oW1   = take((size_t)9 * 32 * 64 * 2);
    size_t oW12  = take((size_t)9 * 64 * 64 * 2);
    size_t oW2   = take((size_t)9 * 32 * 64 * 2);
    size_t oW3   = take((size_t)9 * 64 * 64 * 2);
    size_t oWp   = take((size_t)27 * 64 * 64 * 2);
    size_t oW1f  = take((size_t)f1 * 2);
    size_t oW12f = take((size_t)f12 * 2);
    size_t oW2f  = take((size_t)f2s * 2);
    size_t oW3f  = take((size_t)f3 * 2);
    size_t oWpf  = take((size_t)fp * 2);
    size_t oPa   = take((size_t)Ea * 4);
    size_t oPb   = take((size_t)Eb * 4);
    size_t oPp   = take((size_t)Ep * 4);
    size_t oCNT  = take(((size_t)2 * N + 4 * M + 512) * 4);
    const size_t oDyn = off;

    float* A0    = (float*)(base + oA0);
    float* A1    = (float*)(base + oA1);
    short* t_bf  = (short*)(base + oSh);
    short* x_bf  = (short*)(base + oxb);
    short* W1b   = (short*)(base + oW1);
    short* W12b  = (short*)(base + oW12);
    short* W2b   = (short*)(base + oW2);
    short* W3b   = (short*)(base + oW3);
    short* Wpb   = (short*)(base + oWp);
    short* W1f   = (short*)(base + oW1f);
    short* W12f  = (short*)(base + oW12f);
    short* W2f   = (short*)(base + oW2f);
    short* W3f   = (short*)(base + oW3f);
    short* Wpf   = (short*)(base + oWpf);
    int*   pos_a = (int*)(base + oPa);
    int*   pos_b = (int*)(base + oPb);
    int*   pos_p = (int*)(base + oPp);
    int*   Cbase = (int*)(base + oCNT);
    int*   Ca    = Cbase;
    int*   Cb    = Cbase + N;
    int*   Cp    = Cbase + 2 * N;                 // [4][M] max
    float* stats = (float*)(Cbase + 2 * N + 4 * M);
    short* yslot = (short*)(base + oDyn);

    const size_t avail = (ws_size > oDyn) ? (ws_size - oDyn) : 0;
    long cA = (long)(avail / ((size_t)N * 128));
    long cPmax = (long)(avail / ((size_t)M * 128));
    const int capAB = (int)(cA < 16 ? cA : 16);
    int nchunk, capP;
    if (cPmax >= 48) { nchunk = 2; capP = (int)(cPmax < 64 ? cPmax : 64); }
    else             { nchunk = 4; capP = (int)(cPmax < 40 ? cPmax : 40); }

    dim3 blk(256);
    const int tilesPerK = (P + 15) / 16;
    const int TPW = 4;
    const int wavesPerK = (tilesPerK + TPW - 1) / TPW;
    auto nConvBlocks = [&](int nk) { return (nk * wavesPerK + 3) / 4; };
    auto gRows  = [](int nr) { return dim3((unsigned)((nr + 3) / 4)); };
    auto rsvBlocks = [](int lo, int hi) { return (hi - lo + 2047) / 2048; };
    const int nx = N * 32, n1 = 9*32*64, n12 = 9*64*64, n2 = 9*32*64, n3 = 9*64*64, np = 27*64*64;
    const size_t fbytes = (size_t)N * 64 * sizeof(float);

    // pool chunk boundaries (offset space) + classification constants
    int kc[5];
    int k1v, k2v, k3v;
    if (nchunk == 2) {
        kc[0] = 0; kc[1] = (Kp + 1) / 2; kc[2] = Kp;
        k1v = kc[1]; k2v = Kp + 1; k3v = Kp + 1;
    } else {
        kc[0] = 0; kc[1] = (Kp + 3) / 4; kc[2] = (2 * Kp + 3) / 4; kc[3] = (3 * Kp + 3) / 4; kc[4] = Kp;
        k1v = kc[1]; k2v = kc[2]; k3v = kc[3];
    }
    // pool reserve halves (entry space, 2048-aligned)
    const int sp1 = ((Ep / 2) / 2048) * 2048;

    hipMemsetAsync(Cbase, 0, ((size_t)2 * N + 4 * M + 512) * 4, stream);
    hipMemsetAsync(A0, 0, 2 * fbytes, stream);                 // A0 + A1
    hipMemsetAsync(d_out, 0, (size_t)out_size * 4, stream);    // resB + resA

    const bool slotPath = (capAB >= 8 && capP >= 24);
    const int CB = 1024;

    {
        const int rbA = slotPath ? rsvBlocks(0, Ea) : 0;
        const int rbB = slotPath ? rsvBlocks(0, Eb) : 0;
        prep<<<dim3((unsigned)(CB + rbA + rbB)), blk, 0, stream>>>(
            x, x_bf, nx,
            W1, W1b, W1f, slotPath ? 0 : n1,  slotPath ? f1  : 0,
            W12, W12b, W12f, slotPath ? 0 : n12, slotPath ? f12 : 0,
            W2, W2b, W2f, slotPath ? 0 : n2,  slotPath ? f2s : 0,
            W3, W3b, W3f, slotPath ? 0 : n3,  slotPath ? f3  : 0,
            Wp, Wpb, Wpf, slotPath ? 0 : np,  slotPath ? fp  : 0,
            CB,
            slotPath ? rb_a_out : nullptr, Ea, Ca, pos_a, rbA,
            rb_b_out, Eb, Cb, pos_b);
    }

    if (slotPath) {
        float* st0 = stats, *st1 = stats + 128, *st2 = stats + 256, *st3 = stats + 384;
        const int cb = nConvBlocks(Ka);

        // stage 1: conv1 (rb_a, x) -> A0 ; carries pool reserve 1/2
        spconv_slot<32, false><<<dim3((unsigned)(cb + rsvBlocks(0, sp1))), blk, 0, stream>>>(
            x_bf, W1f, rb_a_in, rb_a_out, pos_a, P, 0, Ka, tilesPerK, wavesPerK, TPW, capAB, yslot, A0,
            cb, rb_p_out, 0, sp1, Cp, pos_p, 2, M, k1v, k2v, k3v);
        reduce_slot<false><<<gRows(N), blk, 0, stream>>>(yslot, Ca, capAB, A0, N, 0);
        bn_stats<<<256, blk, 0, stream>>>(A0, N, st0);
        bn_apply<<<512, blk, 0, stream>>>(A0, st0, g0, b0, t_bf, N, 1);   // zero A0 for stage 3

        // stage 2: conv1_2 (rb_b, t_bf) -> A1 raw ; carries pool reserve 2/2
        spconv_slot<64, false><<<dim3((unsigned)(cb + rsvBlocks(sp1, Ep))), blk, 0, stream>>>(
            t_bf, W12f, rb_b_in, rb_b_out, pos_b, P, 0, Ka, tilesPerK, wavesPerK, TPW, capAB, yslot, A1,
            cb, rb_p_out, sp1, Ep, Cp, pos_p, 2, M, k1v, k2v, k3v);
        reduce_slot<false><<<gRows(N), blk, 0, stream>>>(yslot, Cb, capAB, A1, N, 0);
        bn_stats<<<256, blk, 0, stream>>>(A1, N, st1);

        // stage 3: conv2 (rb_b, x) -> A0
        spconv_slot<32, false><<<dim3((unsigned)cb), blk, 0, stream>>>(
            x_bf, W2f, rb_b_in, rb_b_out, pos_b, P, 0, Ka, tilesPerK, wavesPerK, TPW, capAB, yslot, A0,
            cb, nullptr, 0, 0, nullptr, nullptr, 0, 0, 0, 0, 0);
        reduce_slot<false><<<gRows(N), blk, 0, stream>>>(yslot, Cb, capAB, A0, N, 0);
        bn_stats<<<256, blk, 0, stream>>>(A0, N, st2);
        bn_apply<<<512, blk, 0, stream>>>(A0, st2, g1, b1, t_bf, N, 0);

        // stage 4: conv3 (rb_a, t_bf) -> resA (true)
        spconv_slot<64, true><<<dim3((unsigned)cb), blk, 0, stream>>>(
            t_bf, W3f, rb_a_in, rb_a_out, pos_a, P, 0, Ka, tilesPerK, wavesPerK, TPW, capAB, yslot, resA,
            cb, nullptr, 0, 0, nullptr, nullptr, 0, 0, 0, 0, 0);
        reduce_slot<true><<<gRows(N), blk, 0, stream>>>(yslot, Ca, capAB, resA, N, 0);
        bn_stats<<<256, blk, 0, stream>>>(resA, N, st3);          // TRUE-indexed

        apply4<<<512, blk, 0, stream>>>(resA, st3, g2, b2, A1, st1, g02, b02, t_bf, N);

        // pool conv (rb_p), nchunk chunks -> resB (true)
        for (int c = 0; c < nchunk; ++c) {
            const int pcb = nConvBlocks(kc[c + 1] - kc[c]);
            spconv_slot<64, true><<<dim3((unsigned)pcb), blk, 0, stream>>>(
                t_bf, Wpf, rb_p_in, rb_p_out, pos_p, P, kc[c], kc[c + 1], tilesPerK, wavesPerK, TPW, capP, yslot, resB,
                pcb, nullptr, 0, 0, nullptr, nullptr, 0, 0, 0, 0, 0);
            reduce_slot<true><<<gRows(M), blk, 0, stream>>>(yslot, Cp + c * M, capP, resB, M, c > 0);
        }
    } else {
        // -------- atomic fallback --------
        const int TPW2 = 16;
        const int wPK = (tilesPerK + TPW2 - 1) / TPW2;
        auto cblocks = [&](int K) { return dim3((unsigned)((K * wPK + 3) / 4)); };
        float* st = stats;

        spconv_mfma<32><<<cblocks(Ka), blk, 0, stream>>>(x_bf, W1b, rb_a_in, rb_a_out, P, tilesPerK, wPK, Ka, TPW2, A0);
        bn_stats<<<256, blk, 0, stream>>>(A0, N, st);
        bn_apply_fb<<<512, blk, 0, stream>>>(A0, st, g0, b0, nullptr, t_bf, N);

        spconv_mfma<64><<<cblocks(Ka), blk, 0, stream>>>(t_bf, W12b, rb_b_in, rb_b_out, P, tilesPerK, wPK, Ka, TPW2, A1);
        bn_stats<<<256, blk, 0, stream>>>(A1, N, st + 128);
        bn_apply_fb<<<512, blk, 0, stream>>>(A1, st + 128, g02, b02, A1, nullptr, N);

        hipMemsetAsync(A0, 0, fbytes, stream);
        spconv_mfma<32><<<cblocks(Ka), blk, 0, stream>>>(x_bf, W2b, rb_b_in, rb_b_out, P, tilesPerK, wPK, Ka, TPW2, A0);
        bn_stats<<<256, blk, 0, stream>>>(A0, N, st + 256);
        bn_apply_fb<<<512, blk, 0, stream>>>(A0, st + 256, g1, b1, nullptr, t_bf, N);

        spconv_mfma<64><<<cblocks(Ka), blk, 0, stream>>>(t_bf, W3b, rb_a_in, rb_a_out, P, tilesPerK, wPK, Ka, TPW2, resA);
        bn_stats<<<256, blk, 0, stream>>>(resA, N, st + 384);
        bn_apply_fb<<<512, blk, 0, stream>>>(resA, st + 384, g2, b2, resA, nullptr, N);
        add_copy<<<512, blk, 0, stream>>>(resA, A1, t_bf, N);

        spconv_mfma<64><<<cblocks(Kp), blk, 0, stream>>>(t_bf, Wpb, rb_p_in, rb_p_out, P, tilesPerK, wPK, Kp, TPW2, resB);
    }
}